// Round 15
// baseline (488.790 us; speedup 1.0000x reference)
//
#include <hip/hip_runtime.h>

#define B_SZ 1024
#define T_SZ 128
#define HID 512
#define LAB 100

// ---- d_ws layout (byte offsets) ----
#define OFF_XC    0u          // uchar2 t-major [128][1024][2] = 256 KB
#define OFF_WH    262144u     // ushort[262144] bf16 Wh        = 512 KB
#define OFF_FC2   786432u     // ushort[51200]  bf16 fc2
#define OFF_FC2B  888832u     // float[100] (+pad)
#define OFF_WEFFT 889344u     // float[128][512] Weff^T        = 256 KB
#define OFF_BEFF  1151488u    // float[512]
#define OFF_ELEN  1153536u    // ushort[256][512] bf16 N-PERMUTED = 256 KB
#define OFF_EIPD  1415680u    // ushort[256][512] bf16 N-PERMUTED = 256 KB
#define OFF_FLAGS 1677824u    // uint[4]: flagW
#define WS_NEED   1677840u

typedef __attribute__((ext_vector_type(8))) short short8;
typedef __attribute__((ext_vector_type(8))) unsigned short us8;
typedef __attribute__((ext_vector_type(4))) float float4v;
typedef __attribute__((ext_vector_type(4))) unsigned short us4;
typedef __attribute__((ext_vector_type(8))) __bf16 bf8_t;
typedef unsigned long long ull;

__device__ __attribute__((aligned(16))) unsigned char g_blob[WS_NEED]; // fallback only

__device__ __forceinline__ float bf2f(unsigned short u) {
    union { unsigned int i; float f; } z; z.i = ((unsigned int)u) << 16; return z.f;
}
__device__ __forceinline__ unsigned short f2bf(float f) {
    union { float f; unsigned int i; } z; z.f = f;
    unsigned int r = z.i + 0x7FFFu + ((z.i >> 16) & 1u);
    return (unsigned short)(r >> 16);
}
__device__ __forceinline__ float4v mfma16(short8 a, short8 b, float4v c) {
    return __builtin_amdgcn_mfma_f32_16x16x32_bf16(
        __builtin_bit_cast(bf8_t, a), __builtin_bit_cast(bf8_t, b), c, 0, 0, 0);
}

// ---------------------------------------------------------------------------
// K12 (1191 blocks x 256): ALL prep in one launch (r13-proven flag protocol;
// saves the k1 launch gap and overlaps weff with the elementwise roles).
// Roles (ascending blockIdx = dependency order; no dynamic LDS anywhere):
//  [0,64)      WEFF: Weff^T[k][n] = sum_j x2h[n][j]*fc1[j][k]   -> flagW +=1
//  [64,66)     BEFF: beff[n] (f32 exact)                        -> flagW +=1
//  [66,322)    TABLE: spin flagW==66; bf16 tables, N-PERMUTED (r13-verified)
//  [322,578)   XC:   x -> uchar2 t-major
//  [578,1191)  CONV: bf16 Wh, fc2; fc2b copy
// flagW zeroed by hipMemsetAsync before launch (graph-safe).
// ---------------------------------------------------------------------------
__launch_bounds__(256)
__global__ void k12_kernel(const float* __restrict__ fc1_f, const float* __restrict__ fc1b_f,
                           const float* __restrict__ x2h_f, const float* __restrict__ x2hb_f,
                           const float* __restrict__ h2hb_f,
                           const float* __restrict__ len_f, const float* __restrict__ ipd_f,
                           const int* __restrict__ xi, unsigned char* __restrict__ xc,
                           const float* __restrict__ h2h_f, const float* __restrict__ fc2_f,
                           const float* __restrict__ fc2b_f,
                           float* wefft, float* beff,
                           unsigned short* __restrict__ elen, unsigned short* __restrict__ eipd,
                           unsigned short* __restrict__ o_wh, unsigned short* __restrict__ o_fc2,
                           float* __restrict__ o_fc2b,
                           unsigned int* __restrict__ flags) {
    const int tid = threadIdx.x;
    const int b   = blockIdx.x;
    if (b < 64) {
        // ---------------- WEFF producer (coalesced r11 mapping) ----------
        int gid = b * 256 + tid;              // 0..16383
        int n  = gid >> 5;                    // 0..511 (32 threads per n)
        int k0 = (gid & 31) * 4;
        const float* xr = x2h_f + n * 128;
        float a0 = 0.f, a1 = 0.f, a2 = 0.f, a3 = 0.f;
#pragma unroll 4
        for (int j = 0; j < 128; j++) {
            float xv = xr[j];                                      // broadcast
            float4v fv = *(const float4v*)(fc1_f + j * 128 + k0);  // coalesced
            a0 += xv * fv[0]; a1 += xv * fv[1];
            a2 += xv * fv[2]; a3 += xv * fv[3];
        }
        wefft[(k0 + 0) * 512 + n] = a0;
        wefft[(k0 + 1) * 512 + n] = a1;
        wefft[(k0 + 2) * 512 + n] = a2;
        wefft[(k0 + 3) * 512 + n] = a3;
        __syncthreads();
        if (tid == 0) {
            __threadfence();
            __hip_atomic_fetch_add(&flags[0], 1u, __ATOMIC_RELEASE, __HIP_MEMORY_SCOPE_SYSTEM);
        }
        return;
    }
    if (b < 66) {
        // ---------------- BEFF producer ----------------
        int tg = (b - 64) * 256 + tid;        // 0..511
        float s = x2hb_f[tg] + h2hb_f[tg];
        const float4v* xr = (const float4v*)(x2h_f + tg * 128);
        const float4v* bb = (const float4v*)fc1b_f;
        for (int j = 0; j < 32; j++) {
            float4v a = xr[j], c = bb[j];
            s += a[0] * c[0] + a[1] * c[1] + a[2] * c[2] + a[3] * c[3];
        }
        beff[tg] = s;
        __syncthreads();
        if (tid == 0) {
            __threadfence();
            __hip_atomic_fetch_add(&flags[0], 1u, __ATOMIC_RELEASE, __HIP_MEMORY_SCOPE_SYSTEM);
        }
        return;
    }
    if (b < 322) {
        // ---------------- TABLE builder (spins on flagW) ----------------
        if (tid == 0) {
            while (__hip_atomic_load(&flags[0], __ATOMIC_RELAXED, __HIP_MEMORY_SCOPE_SYSTEM) < 66u)
                __builtin_amdgcn_s_sleep(8);
            __threadfence();   // acquire: wefft/beff reads below
        }
        __syncthreads();
        int grp = (b - 66) * 256 + tid;        // 0..65535
        int tab = grp >> 15;                   // 0: len, 1: ipd
        int g2  = grp & 32767;
        int v   = g2 >> 7;
        int nq  = (g2 & 127) * 4;              // logical n base (4 consecutive)
        const float* emb = (tab ? ipd_f : len_f) + v * 64;
        const float* wt  = wefft + tab * 64 * 512 + nq;
        float a0 = 0.f, a1 = 0.f, a2 = 0.f, a3 = 0.f;
#pragma unroll 8
        for (int k = 0; k < 64; k++) {
            float e = emb[k];
            float4v w = *(const float4v*)(wt + k * 512);
            a0 += e * w[0]; a1 += e * w[1]; a2 += e * w[2]; a3 += e * w[3];
        }
        if (tab) {
            float4v b4 = *(const float4v*)&beff[nq];
            a0 += b4[0]; a1 += b4[1]; a2 += b4[2]; a3 += b4[3];
        }
        // permuted store (r13-verified bijection)
        int nt = (nq >> 4) & 3, qq = (nq >> 2) & 3;
        int p0 = (nq & ~63) + ((nt >> 1) << 5) + qq * 8 + ((nt & 1) << 2);
        us4 o = { f2bf(a0), f2bf(a1), f2bf(a2), f2bf(a3) };
        unsigned short* dst = tab ? eipd : elen;
        *(us4*)&dst[v * 512 + p0] = o;
        return;
    }
    if (b < 578) {
        // ---------------- XC role ----------------
        __shared__ int is64;
        if (tid == 0) {
            int nz = 0;
            for (int j = 1; j < 64; j += 2) nz |= xi[j];
            is64 = (nz == 0) ? 1 : 0;
        }
        __syncthreads();
        const int n = B_SZ * T_SZ * 2;
        const int i64 = is64;
        for (int i = (b - 322) * 256 + tid; i < n; i += 256 * 256) {
            int v = i64 ? xi[2 * i] : xi[i];
            v = v < 0 ? 0 : (v > 255 ? 255 : v);
            int bb2 = i >> 8, r = i & 255, t = r >> 1, c = r & 1;
            xc[t * 2048 + bb2 * 2 + c] = (unsigned char)v;
        }
        return;
    }
    // ---------------- CONV role ----------------
    const int N2 = 262144, N3 = 51200, N5 = 100;
    const int total = N2 + N3 + N5;
    for (int i = (b - 578) * 256 + tid; i < total; i += 613 * 256) {
        int j = i;
        if (j < N2) { o_wh[j] = f2bf(h2h_f[j]); continue; }
        j -= N2;
        if (j < N3) { o_fc2[j] = f2bf(fc2_f[j]); continue; }
        j -= N3;
        o_fc2b[j] = fc2b_f[j];
    }
}

// ---------------------------------------------------------------------------
// RNN v9: r14 structure with Wh kt0..13 in 224 AGPRs (was 12/192) and sA
// shrunk to kt14..15 (64 KB LDS, was 128). LDS reads/step 256 -> 192 KB —
// the dominant pipe (≈3070 of ~5175 cyc/step). DELIBERATE probe at the
// 320-reg/wave cliff (640-reg/SIMD pool @ 2 waves/SIMD): needs VGPR <= 96
// beside 224 AGPR (compiler may move acc to AGPR: 240 <= 256).
// TRIPWIRE: WRITE_SIZE must stay 784 KB; if MBs -> spill -> revert to 12-kt.
// sA 2-kt swizzle: slot c=(kt-14)*4+q, swizzled (c ^ (r&7))&7, row stride 64;
// decomposed: fbase2=(n0+mcol)*64+qlo, ej2[j]=((j*4)^(mcol&4))*8 (disjoint
// bits, bank-checked 2-way = free). Gather/pipeline identical to r14.
// LDS total = 64 + 32 = 96 KB.
// ---------------------------------------------------------------------------
__launch_bounds__(512, 2)
__global__ void rnn_kernel(const unsigned short* __restrict__ w_wh,
                           const unsigned char* __restrict__ w_xc,
                           const unsigned short* __restrict__ w_elen,
                           const unsigned short* __restrict__ w_eipd,
                           const unsigned short* __restrict__ w_fc2,
                           const float* __restrict__ w_fc2b,
                           float* __restrict__ out) {
    extern __shared__ unsigned short sm2[];
    unsigned short* sA = sm2;            // Wh k 448..511: 32768 ushorts (64 KB)
    unsigned short* sH = sm2 + 32768;    // h dbuf: 2 x 8192 ushorts (32 KB)

    const int tid  = threadIdx.x;
    const int wv   = tid >> 6;           // 0..7
    const int ln   = tid & 63;
    const int mcol = ln & 15;            // batch col within block
    const int q    = ln >> 4;
    const int g    = blockIdx.x;
    const int b0   = g * 16;
    const int n0   = wv * 64;            // wave owns hidden rows n0..n0+63

    // ---- stage Wh kt 14..15 into LDS (swizzled, 8 slots/row) ----
    for (int it = 0; it < 8; it++) {
        int chunk = it * 512 + tid;          // 0..4095
        int r = chunk >> 3, c = chunk & 7;
        uint4 v = *(const uint4*)(w_wh + r * 512 + 448 + c * 8);
        *(uint4*)&sA[r * 64 + ((c ^ (r & 7)) & 7) * 8] = v;
    }
    // ---- zero h buffer 0 ----
    {
        uint4 z = {0, 0, 0, 0};
        *(uint4*)&sH[tid * 8] = z;
        *(uint4*)&sH[(512 + tid) * 8] = z;
    }
    // ---- Wh kt 0..13 into registers: 56 frags = 224 regs (AGPR) ----
    short8 whr[4][14];
#pragma unroll
    for (int nt = 0; nt < 4; nt++)
#pragma unroll
        for (int kt = 0; kt < 14; kt++)
            whr[nt][kt] = *(const short8*)(w_wh + (n0 + nt * 16 + mcol) * 512 + kt * 32 + q * 8);

    // ---- strength-reduced swizzle offsets (ushort units) ----
    const int qlo = (q ^ (mcol & 3)) * 8;
    int ej[4];
#pragma unroll
    for (int j = 0; j < 4; j++)
        ej[j] = ((j * 4) ^ (mcol & 12)) * 8;
    int ej2[2];
#pragma unroll
    for (int j = 0; j < 2; j++)
        ej2[j] = ((j * 4) ^ (mcol & 4)) * 8;
    const int base_b = mcol * 512 + qlo;          // h-read base
    const int fbase  = (n0 + mcol) * 64 + qlo;    // sA-read base (row stride 64)
    int hw_off[4];
#pragma unroll
    for (int nt = 0; nt < 4; nt++) {
        int n = n0 + nt * 16 + q * 4;
        hw_off[nt] = mcol * 512 + (((n >> 3) ^ mcol) & 63) * 8 + (n & 7);
    }

    // ---- gather pipeline prologue (permuted bf16 tables, uchar2 idx) ----
    const int xb2  = (b0 + mcol) * 2;     // byte offset within a t-slice
    const int ecol = n0 + q * 8;          // permuted window offset
    us8 tL0, tL1, tI0, tI1;
    {
        unsigned int i0 = *(const unsigned short*)&w_xc[xb2];          // x[t=0]
        const unsigned short* eL = w_elen + (i0 & 255u) * 512 + ecol;
        const unsigned short* eI = w_eipd + (i0 >> 8) * 512 + ecol;
        tL0 = *(const us8*)eL;  tL1 = *(const us8*)(eL + 32);
        tI0 = *(const us8*)eI;  tI1 = *(const us8*)(eI + 32);
    }
    unsigned int idxP = *(const unsigned short*)&w_xc[2048 + xb2];     // x[t=1]

    __syncthreads();

    for (int t = 0; t < T_SZ; t++) {
        const unsigned short* hRd = sH + ((t & 1) << 13);
        unsigned short* hWr = sH + (((t + 1) & 1) << 13);

        // ---- acc init: unpack permuted us8 pairs (loads from t-1, landed) --
        float4v acc[4];
#pragma unroll
        for (int r = 0; r < 4; r++) {
            acc[0][r] = bf2f(tL0[r])     + bf2f(tI0[r]);
            acc[1][r] = bf2f(tL0[4 + r]) + bf2f(tI0[4 + r]);
            acc[2][r] = bf2f(tL1[r])     + bf2f(tI1[r]);
            acc[3][r] = bf2f(tL1[4 + r]) + bf2f(tI1[4 + r]);
        }
        // ---- issue next-step table loads (idxP resident -> no chain) ----
        if (t + 1 < T_SZ) {
            const unsigned short* eL = w_elen + (idxP & 255u) * 512 + ecol;
            const unsigned short* eI = w_eipd + (idxP >> 8) * 512 + ecol;
            tL0 = *(const us8*)eL;  tL1 = *(const us8*)(eL + 32);
            tI0 = *(const us8*)eI;  tI1 = *(const us8*)(eI + 32);
            if (t + 2 < T_SZ)
                idxP = *(const unsigned short*)&w_xc[(t + 2) * 2048 + xb2];
        }

        // ---- Wh MFMAs: kt 0..13 from regs ----
#pragma unroll
        for (int kt = 0; kt < 14; kt++) {
            short8 bh = *(const short8*)&hRd[base_b + ej[kt & 3] + (kt >> 2) * 128];
#pragma unroll
            for (int nt = 0; nt < 4; nt++)
                acc[nt] = mfma16(whr[nt][kt], bh, acc[nt]);
        }
        // ---- kt 14..15 from LDS ----
#pragma unroll
        for (int j = 0; j < 2; j++) {
            short8 bh = *(const short8*)&hRd[base_b + ej[2 + j] + 384];
#pragma unroll
            for (int nt = 0; nt < 4; nt++) {
                short8 fa = *(const short8*)&sA[fbase + nt * 1024 + ej2[j]];
                acc[nt] = mfma16(fa, bh, acc[nt]);
            }
        }

        // ---- fast tanh -> bf16, write h(t+1) into other buffer ----
#pragma unroll
        for (int nt = 0; nt < 4; nt++) {
            unsigned short o[4];
#pragma unroll
            for (int r = 0; r < 4; r++) {
                float e  = __expf(2.0f * acc[nt][r]);
                float th = 1.0f - 2.0f * __builtin_amdgcn_rcpf(e + 1.0f);
                o[r] = f2bf(th);
            }
            us4 v4 = { o[0], o[1], o[2], o[3] };
            *(us4*)&hWr[hw_off[nt]] = v4;
        }
        __syncthreads();   // h(t+1) visible to all waves before next step
    }

    // final h is in buffer 0 (T_SZ even)
    unsigned short* hF = sH;

    // ---- fc2 epilogue: waves 0..6 cover 112 >= 100 labels ----
    if (wv < 7) {
        int lA = wv * 16 + mcol; if (lA > 99) lA = 99;
        float4v a2 = {0.f, 0.f, 0.f, 0.f};
#pragma unroll
        for (int kt = 0; kt < 16; kt++) {
            short8 fa = *(const short8*)(w_fc2 + lA * 512 + kt * 32 + q * 8);
            short8 bh = *(const short8*)&hF[base_b + ej[kt & 3] + (kt >> 2) * 128];
            a2 = mfma16(fa, bh, a2);
        }
#pragma unroll
        for (int r = 0; r < 4; r++) {
            int l = wv * 16 + q * 4 + r;
            if (l < 100) out[(b0 + mcol) * 100 + l] = a2[r] + w_fc2b[l];
        }
    }
}

extern "C" void kernel_launch(void* const* d_in, const int* in_sizes, int n_in,
                              void* d_out, int out_size, void* d_ws, size_t ws_size,
                              hipStream_t stream) {
    unsigned char* base = (unsigned char*)d_ws;
    if (ws_size < (size_t)WS_NEED) {
        void* p = nullptr;
        hipGetSymbolAddress(&p, HIP_SYMBOL(g_blob));
        base = (unsigned char*)p;
    }
    unsigned char*  w_xc    = base + OFF_XC;
    unsigned short* w_wh    = (unsigned short*)(base + OFF_WH);
    unsigned short* w_fc2   = (unsigned short*)(base + OFF_FC2);
    float*          w_fc2b  = (float*)(base + OFF_FC2B);
    float*          w_wefft = (float*)(base + OFF_WEFFT);
    float*          w_beff  = (float*)(base + OFF_BEFF);
    unsigned short* w_elen  = (unsigned short*)(base + OFF_ELEN);
    unsigned short* w_eipd  = (unsigned short*)(base + OFF_EIPD);
    unsigned int*   w_flags = (unsigned int*)(base + OFF_FLAGS);

    static bool attr_set = false;
    if (!attr_set) {
        hipFuncSetAttribute((const void*)rnn_kernel,
                            hipFuncAttributeMaxDynamicSharedMemorySize, 98304);
        attr_set = true;
    }

    hipMemsetAsync(w_flags, 0, 16, stream);
    k12_kernel<<<1191, 256, 0, stream>>>(
        (const float*)d_in[3], (const float*)d_in[4],
        (const float*)d_in[5], (const float*)d_in[6], (const float*)d_in[8],
        (const float*)d_in[1], (const float*)d_in[2],
        (const int*)d_in[0], w_xc,
        (const float*)d_in[7], (const float*)d_in[9], (const float*)d_in[10],
        w_wefft, w_beff, w_elen, w_eipd, w_wh, w_fc2, w_fc2b,
        w_flags);
    rnn_kernel<<<64, 512, 98304, stream>>>(
        w_wh, w_xc, w_elen, w_eipd, w_fc2, w_fc2b, (float*)d_out);
}

// Round 16
// 440.255 us; speedup vs baseline: 1.1102x; 1.1102x over previous
//
#include <hip/hip_runtime.h>

#define B_SZ 1024
#define T_SZ 128
#define HID 512
#define LAB 100

// ---- d_ws layout (byte offsets) ----
#define OFF_XC    0u          // uchar2 t-major [128][1024][2] = 256 KB
#define OFF_WH    262144u     // ushort[262144] bf16 Wh        = 512 KB
#define OFF_FC2   786432u     // ushort[51200]  bf16 fc2
#define OFF_FC2B  888832u     // float[100] (+pad)
#define OFF_WEFFT 889344u     // float[128][512] Weff^T        = 256 KB
#define OFF_BEFF  1151488u    // float[512]
#define OFF_ELEN  1153536u    // ushort[256][512] bf16 N-PERMUTED = 256 KB
#define OFF_EIPD  1415680u    // ushort[256][512] bf16 N-PERMUTED = 256 KB
#define OFF_FLAGS 1677824u    // uint[4]: flagT
#define WS_NEED   1677840u

typedef __attribute__((ext_vector_type(8))) short short8;
typedef __attribute__((ext_vector_type(8))) unsigned short us8;
typedef __attribute__((ext_vector_type(4))) float float4v;
typedef __attribute__((ext_vector_type(4))) unsigned short us4;
typedef __attribute__((ext_vector_type(8))) __bf16 bf8_t;
typedef unsigned long long ull;

__device__ __attribute__((aligned(16))) unsigned char g_blob[WS_NEED]; // fallback only

__device__ __forceinline__ float bf2f(unsigned short u) {
    union { unsigned int i; float f; } z; z.i = ((unsigned int)u) << 16; return z.f;
}
__device__ __forceinline__ unsigned short f2bf(float f) {
    union { float f; unsigned int i; } z; z.f = f;
    unsigned int r = z.i + 0x7FFFu + ((z.i >> 16) & 1u);
    return (unsigned short)(r >> 16);
}
__device__ __forceinline__ float4v mfma16(short8 a, short8 b, float4v c) {
    return __builtin_amdgcn_mfma_f32_16x16x32_bf16(
        __builtin_bit_cast(bf8_t, a), __builtin_bit_cast(bf8_t, b), c, 0, 0, 0);
}

// ---------------------------------------------------------------------------
// K0 (935 blocks x 256): everything with NO internal dependencies — all the
// data the rnn PROLOGUE needs (bf16 Wh) plus weff/beff/xc.
//  [0,64)    WEFF: Weff^T[k][n] = sum_j x2h[n][j]*fc1[j][k] (coalesced r11)
//  [64,66)   BEFF: beff[n] = x2hb+h2hb+x2h.fc1b (f32 exact)
//  [66,322)  XC:   x -> uchar2 t-major
//  [322,935) CONV: bf16 Wh, fc2; fc2b copy
// ---------------------------------------------------------------------------
__launch_bounds__(256)
__global__ void k0_kernel(const float* __restrict__ fc1_f, const float* __restrict__ fc1b_f,
                          const float* __restrict__ x2h_f, const float* __restrict__ x2hb_f,
                          const float* __restrict__ h2hb_f,
                          const int* __restrict__ xi, unsigned char* __restrict__ xc,
                          const float* __restrict__ h2h_f, const float* __restrict__ fc2_f,
                          const float* __restrict__ fc2b_f,
                          float* __restrict__ wefft, float* __restrict__ beff,
                          unsigned short* __restrict__ o_wh, unsigned short* __restrict__ o_fc2,
                          float* __restrict__ o_fc2b) {
    const int tid = threadIdx.x;
    const int b   = blockIdx.x;
    if (b < 64) {
        int gid = b * 256 + tid;              // 0..16383
        int n  = gid >> 5;                    // 0..511 (32 threads per n)
        int k0 = (gid & 31) * 4;
        const float* xr = x2h_f + n * 128;
        float a0 = 0.f, a1 = 0.f, a2 = 0.f, a3 = 0.f;
#pragma unroll 4
        for (int j = 0; j < 128; j++) {
            float xv = xr[j];                                      // broadcast
            float4v fv = *(const float4v*)(fc1_f + j * 128 + k0);  // coalesced
            a0 += xv * fv[0]; a1 += xv * fv[1];
            a2 += xv * fv[2]; a3 += xv * fv[3];
        }
        wefft[(k0 + 0) * 512 + n] = a0;
        wefft[(k0 + 1) * 512 + n] = a1;
        wefft[(k0 + 2) * 512 + n] = a2;
        wefft[(k0 + 3) * 512 + n] = a3;
        return;
    }
    if (b < 66) {
        int tg = (b - 64) * 256 + tid;        // 0..511
        float s = x2hb_f[tg] + h2hb_f[tg];
        const float4v* xr = (const float4v*)(x2h_f + tg * 128);
        const float4v* bb = (const float4v*)fc1b_f;
        for (int j = 0; j < 32; j++) {
            float4v a = xr[j], c = bb[j];
            s += a[0] * c[0] + a[1] * c[1] + a[2] * c[2] + a[3] * c[3];
        }
        beff[tg] = s;
        return;
    }
    if (b < 322) {
        __shared__ int is64;
        if (tid == 0) {
            int nz = 0;
            for (int j = 1; j < 64; j += 2) nz |= xi[j];
            is64 = (nz == 0) ? 1 : 0;
        }
        __syncthreads();
        const int n = B_SZ * T_SZ * 2;
        const int i64 = is64;
        for (int i = (b - 66) * 256 + tid; i < n; i += 256 * 256) {
            int v = i64 ? xi[2 * i] : xi[i];
            v = v < 0 ? 0 : (v > 255 ? 255 : v);
            int bb2 = i >> 8, r = i & 255, t = r >> 1, c = r & 1;
            xc[t * 2048 + bb2 * 2 + c] = (unsigned char)v;
        }
        return;
    }
    const int N2 = 262144, N3 = 51200, N5 = 100;
    const int total = N2 + N3 + N5;
    for (int i = (b - 322) * 256 + tid; i < total; i += 613 * 256) {
        int j = i;
        if (j < N2) { o_wh[j] = f2bf(h2h_f[j]); continue; }
        j -= N2;
        if (j < N3) { o_fc2[j] = f2bf(fc2_f[j]); continue; }
        j -= N3;
        o_fc2b[j] = fc2b_f[j];
    }
}

// ---------------------------------------------------------------------------
// FUSED (192 blocks x 512, 160 KB dyn LDS -> 1 block/CU, all co-resident):
//  [0,128)  TABLE: builds bf16 N-permuted tables from wefft/beff (k0 outputs,
//           stream-ordered -> NO spin needed) -> release flagT.
//  [128,192) RNN: BYTE-IDENTICAL r14 rnn code (276 us proven; bf16 Wh from
//           workspace — r13 lesson: inline f32 conversion poisons regalloc).
//           Single spin on flagT==128 placed AFTER the Wh staging prologue,
//           right before the gather prologue — table time hides under it.
// Deadlock-free under ANY dispatch order: only spinners are 64 rnn blocks
// (<= 64 CUs), leaving >= 128 CUs for the 128 independent table blocks.
// ---------------------------------------------------------------------------
__launch_bounds__(512, 2)
__global__ void fused_kernel(const float* __restrict__ wefft, const float* __restrict__ beff,
                             const float* __restrict__ len_f, const float* __restrict__ ipd_f,
                             unsigned short* __restrict__ elen, unsigned short* __restrict__ eipd,
                             const unsigned short* __restrict__ w_wh,
                             const unsigned char* __restrict__ w_xc,
                             const unsigned short* __restrict__ w_fc2,
                             const float* __restrict__ w_fc2b,
                             unsigned int* __restrict__ flags,
                             float* __restrict__ out) {
    extern __shared__ unsigned short sm2[];
    const int tid = threadIdx.x;
    const int b   = blockIdx.x;

    if (b < 128) {
        // ---------------- TABLE role (no deps inside this kernel) ----------
        int grp = b * 512 + tid;               // 0..65535
        int tab = grp >> 15;                   // 0: len, 1: ipd
        int g2  = grp & 32767;
        int v   = g2 >> 7;
        int nq  = (g2 & 127) * 4;              // logical n base (4 consecutive)
        const float* emb = (tab ? ipd_f : len_f) + v * 64;
        const float* wt  = wefft + tab * 64 * 512 + nq;
        float a0 = 0.f, a1 = 0.f, a2 = 0.f, a3 = 0.f;
#pragma unroll 8
        for (int k = 0; k < 64; k++) {
            float e = emb[k];
            float4v w = *(const float4v*)(wt + k * 512);
            a0 += e * w[0]; a1 += e * w[1]; a2 += e * w[2]; a3 += e * w[3];
        }
        if (tab) {
            float4v b4 = *(const float4v*)&beff[nq];
            a0 += b4[0]; a1 += b4[1]; a2 += b4[2]; a3 += b4[3];
        }
        // permuted store (r13-verified bijection)
        int nt = (nq >> 4) & 3, qq = (nq >> 2) & 3;
        int p0 = (nq & ~63) + ((nt >> 1) << 5) + qq * 8 + ((nt & 1) << 2);
        us4 o = { f2bf(a0), f2bf(a1), f2bf(a2), f2bf(a3) };
        unsigned short* dst = tab ? eipd : elen;
        *(us4*)&dst[v * 512 + p0] = o;
        __syncthreads();
        if (tid == 0) {
            __threadfence();
            __hip_atomic_fetch_add(&flags[0], 1u, __ATOMIC_RELEASE, __HIP_MEMORY_SCOPE_SYSTEM);
        }
        return;
    }

    // ==================== RNN role (r14-proven, 276 us) =====================
    unsigned short* sA = sm2;            // Wh k 384..511: 65536 ushorts (128 KB)
    unsigned short* sH = sm2 + 65536;    // h dbuf: 2 x 8192 ushorts (32 KB)

    const int wv   = tid >> 6;           // 0..7
    const int ln   = tid & 63;
    const int mcol = ln & 15;            // batch col within block
    const int q    = ln >> 4;
    const int g    = b - 128;
    const int b0   = g * 16;
    const int n0   = wv * 64;            // wave owns hidden rows n0..n0+63

    // ---- stage Wh kt 12..15 into LDS (swizzled) ----
    for (int it = 0; it < 16; it++) {
        int chunk = it * 512 + tid;          // 0..8191
        int r = chunk >> 4, c = chunk & 15;
        uint4 v = *(const uint4*)(w_wh + r * 512 + 384 + c * 8);
        *(uint4*)&sA[r * 128 + ((c ^ (r & 15)) & 15) * 8] = v;
    }
    // ---- zero h buffer 0 ----
    {
        uint4 z = {0, 0, 0, 0};
        *(uint4*)&sH[tid * 8] = z;
        *(uint4*)&sH[(512 + tid) * 8] = z;
    }
    // ---- Wh kt 0..11 into registers: 48 frags = 192 regs (AGPR) ----
    short8 whr[4][12];
#pragma unroll
    for (int nt = 0; nt < 4; nt++)
#pragma unroll
        for (int kt = 0; kt < 12; kt++)
            whr[nt][kt] = *(const short8*)(w_wh + (n0 + nt * 16 + mcol) * 512 + kt * 32 + q * 8);

    // ---- strength-reduced swizzle offsets (ushort units) ----
    const int qlo = (q ^ (mcol & 3)) * 8;
    int ej[4];
#pragma unroll
    for (int j = 0; j < 4; j++)
        ej[j] = ((j * 4) ^ (mcol & 12)) * 8;
    const int base_b = mcol * 512 + qlo;          // h-read base
    const int fbase  = (n0 + mcol) * 128 + qlo;   // sA-read base
    int hw_off[4];
#pragma unroll
    for (int nt = 0; nt < 4; nt++) {
        int n = n0 + nt * 16 + q * 4;
        hw_off[nt] = mcol * 512 + (((n >> 3) ^ mcol) & 63) * 8 + (n & 7);
    }

    // ---- wait for tables (built concurrently under our staging) ----
    if (tid == 0) {
        while (__hip_atomic_load(&flags[0], __ATOMIC_RELAXED, __HIP_MEMORY_SCOPE_SYSTEM) < 128u)
            __builtin_amdgcn_s_sleep(8);
        __threadfence();   // acquire for table reads
    }
    __syncthreads();        // also covers sA/sH staging visibility

    // ---- gather pipeline prologue (permuted bf16 tables, uchar2 idx) ----
    const int xb2  = (b0 + mcol) * 2;     // byte offset within a t-slice
    const int ecol = n0 + q * 8;          // permuted window offset
    us8 tL0, tL1, tI0, tI1;
    {
        unsigned int i0 = *(const unsigned short*)&w_xc[xb2];          // x[t=0]
        const unsigned short* eL = elen + (i0 & 255u) * 512 + ecol;
        const unsigned short* eI = eipd + (i0 >> 8) * 512 + ecol;
        tL0 = *(const us8*)eL;  tL1 = *(const us8*)(eL + 32);
        tI0 = *(const us8*)eI;  tI1 = *(const us8*)(eI + 32);
    }
    unsigned int idxP = *(const unsigned short*)&w_xc[2048 + xb2];     // x[t=1]

    __syncthreads();

    for (int t = 0; t < T_SZ; t++) {
        const unsigned short* hRd = sH + ((t & 1) << 13);
        unsigned short* hWr = sH + (((t + 1) & 1) << 13);

        // ---- acc init: unpack permuted us8 pairs (loads from t-1, landed) --
        float4v acc[4];
#pragma unroll
        for (int r = 0; r < 4; r++) {
            acc[0][r] = bf2f(tL0[r])     + bf2f(tI0[r]);
            acc[1][r] = bf2f(tL0[4 + r]) + bf2f(tI0[4 + r]);
            acc[2][r] = bf2f(tL1[r])     + bf2f(tI1[r]);
            acc[3][r] = bf2f(tL1[4 + r]) + bf2f(tI1[4 + r]);
        }
        // ---- issue next-step table loads (idxP resident -> no chain) ----
        if (t + 1 < T_SZ) {
            const unsigned short* eL = elen + (idxP & 255u) * 512 + ecol;
            const unsigned short* eI = eipd + (idxP >> 8) * 512 + ecol;
            tL0 = *(const us8*)eL;  tL1 = *(const us8*)(eL + 32);
            tI0 = *(const us8*)eI;  tI1 = *(const us8*)(eI + 32);
            if (t + 2 < T_SZ)
                idxP = *(const unsigned short*)&w_xc[(t + 2) * 2048 + xb2];
        }

        // ---- Wh MFMAs: kt 0..11 from regs ----
#pragma unroll
        for (int kt = 0; kt < 12; kt++) {
            short8 bh = *(const short8*)&hRd[base_b + ej[kt & 3] + (kt >> 2) * 128];
#pragma unroll
            for (int nt = 0; nt < 4; nt++)
                acc[nt] = mfma16(whr[nt][kt], bh, acc[nt]);
        }
        // ---- kt 12..15 from LDS ----
#pragma unroll
        for (int j = 0; j < 4; j++) {
            short8 bh = *(const short8*)&hRd[base_b + ej[j] + 384];
#pragma unroll
            for (int nt = 0; nt < 4; nt++) {
                short8 fa = *(const short8*)&sA[fbase + nt * 2048 + ej[j]];
                acc[nt] = mfma16(fa, bh, acc[nt]);
            }
        }

        // ---- fast tanh -> bf16, write h(t+1) into other buffer ----
#pragma unroll
        for (int nt = 0; nt < 4; nt++) {
            unsigned short o[4];
#pragma unroll
            for (int r = 0; r < 4; r++) {
                float e  = __expf(2.0f * acc[nt][r]);
                float th = 1.0f - 2.0f * __builtin_amdgcn_rcpf(e + 1.0f);
                o[r] = f2bf(th);
            }
            us4 v4 = { o[0], o[1], o[2], o[3] };
            *(us4*)&hWr[hw_off[nt]] = v4;
        }
        __syncthreads();   // h(t+1) visible to all waves before next step
    }

    // final h is in buffer 0 (T_SZ even)
    unsigned short* hF = sH;

    // ---- fc2 epilogue: waves 0..6 cover 112 >= 100 labels ----
    if (wv < 7) {
        int lA = wv * 16 + mcol; if (lA > 99) lA = 99;
        float4v a2 = {0.f, 0.f, 0.f, 0.f};
#pragma unroll
        for (int kt = 0; kt < 16; kt++) {
            short8 fa = *(const short8*)(w_fc2 + lA * 512 + kt * 32 + q * 8);
            short8 bh = *(const short8*)&hF[base_b + ej[kt & 3] + (kt >> 2) * 128];
            a2 = mfma16(fa, bh, a2);
        }
#pragma unroll
        for (int r = 0; r < 4; r++) {
            int l = wv * 16 + q * 4 + r;
            if (l < 100) out[(b0 + mcol) * 100 + l] = a2[r] + w_fc2b[l];
        }
    }
}

extern "C" void kernel_launch(void* const* d_in, const int* in_sizes, int n_in,
                              void* d_out, int out_size, void* d_ws, size_t ws_size,
                              hipStream_t stream) {
    unsigned char* base = (unsigned char*)d_ws;
    if (ws_size < (size_t)WS_NEED) {
        void* p = nullptr;
        hipGetSymbolAddress(&p, HIP_SYMBOL(g_blob));
        base = (unsigned char*)p;
    }
    unsigned char*  w_xc    = base + OFF_XC;
    unsigned short* w_wh    = (unsigned short*)(base + OFF_WH);
    unsigned short* w_fc2   = (unsigned short*)(base + OFF_FC2);
    float*          w_fc2b  = (float*)(base + OFF_FC2B);
    float*          w_wefft = (float*)(base + OFF_WEFFT);
    float*          w_beff  = (float*)(base + OFF_BEFF);
    unsigned short* w_elen  = (unsigned short*)(base + OFF_ELEN);
    unsigned short* w_eipd  = (unsigned short*)(base + OFF_EIPD);
    unsigned int*   w_flags = (unsigned int*)(base + OFF_FLAGS);

    static bool attr_set = false;
    if (!attr_set) {
        hipFuncSetAttribute((const void*)fused_kernel,
                            hipFuncAttributeMaxDynamicSharedMemorySize, 163840);
        attr_set = true;
    }

    hipMemsetAsync(w_flags, 0, 16, stream);
    k0_kernel<<<935, 256, 0, stream>>>(
        (const float*)d_in[3], (const float*)d_in[4],
        (const float*)d_in[5], (const float*)d_in[6], (const float*)d_in[8],
        (const int*)d_in[0], w_xc,
        (const float*)d_in[7], (const float*)d_in[9], (const float*)d_in[10],
        w_wefft, w_beff, w_wh, w_fc2, w_fc2b);
    fused_kernel<<<192, 512, 163840, stream>>>(
        w_wefft, w_beff,
        (const float*)d_in[1], (const float*)d_in[2],
        w_elen, w_eipd,
        w_wh, w_xc, w_fc2, w_fc2b,
        w_flags, (float*)d_out);
}

// Round 17
// 356.394 us; speedup vs baseline: 1.3715x; 1.2353x over previous
//
#include <hip/hip_runtime.h>

#define B_SZ 1024
#define T_SZ 128
#define HID 512
#define LAB 100

// ---- d_ws layout (byte offsets) ----
#define OFF_XC    0u          // uchar2 t-major [128][1024][2] = 256 KB
#define OFF_WH    262144u     // ushort[262144] bf16 Wh        = 512 KB
#define OFF_FC2   786432u     // ushort[51200]  bf16 fc2
#define OFF_FC2B  888832u     // float[100] (+pad)
#define OFF_WEFFT 889344u     // float[128][512] Weff^T        = 256 KB
#define OFF_BEFF  1151488u    // float[512]
#define OFF_ELEN  1153536u    // ushort[256][512] bf16 N-PERMUTED = 256 KB
#define OFF_EIPD  1415680u    // ushort[256][512] bf16 N-PERMUTED = 256 KB
#define WS_NEED   1677824u

typedef __attribute__((ext_vector_type(8))) short short8;
typedef __attribute__((ext_vector_type(8))) unsigned short us8;
typedef __attribute__((ext_vector_type(4))) float float4v;
typedef __attribute__((ext_vector_type(4))) unsigned short us4;
typedef __attribute__((ext_vector_type(8))) __bf16 bf8_t;
typedef unsigned long long ull;

__device__ __attribute__((aligned(16))) unsigned char g_blob[WS_NEED]; // fallback only

__device__ __forceinline__ float bf2f(unsigned short u) {
    union { unsigned int i; float f; } z; z.i = ((unsigned int)u) << 16; return z.f;
}
__device__ __forceinline__ unsigned short f2bf(float f) {
    union { float f; unsigned int i; } z; z.f = f;
    unsigned int r = z.i + 0x7FFFu + ((z.i >> 16) & 1u);
    return (unsigned short)(r >> 16);
}
__device__ __forceinline__ float4v mfma16(short8 a, short8 b, float4v c) {
    return __builtin_amdgcn_mfma_f32_16x16x32_bf16(
        __builtin_bit_cast(bf8_t, a), __builtin_bit_cast(bf8_t, b), c, 0, 0, 0);
}

// ---------------------------------------------------------------------------
// K1 (66 blocks x 256): work that must precede the table build (r11-proven).
//  [0,64) : Weff^T[k][n] coalesced mapping (broadcast x2h + float4 fc1 rows)
//  [64,66): beff[n] = x2hb[n]+h2hb[n]+sum_j x2h[n][j]*fc1b[j]  (f32 exact)
// ---------------------------------------------------------------------------
__launch_bounds__(256)
__global__ void k1_kernel(const float* __restrict__ fc1_f, const float* __restrict__ fc1b_f,
                          const float* __restrict__ x2h_f, const float* __restrict__ x2hb_f,
                          const float* __restrict__ h2hb_f,
                          float* __restrict__ wefft, float* __restrict__ beff) {
    const int tid = threadIdx.x;
    if (blockIdx.x < 64) {
        int gid = blockIdx.x * 256 + tid;     // 0..16383
        int n  = gid >> 5;                    // 0..511 (32 threads per n)
        int k0 = (gid & 31) * 4;              // 0,4,...,124
        const float* xr = x2h_f + n * 128;
        float a0 = 0.f, a1 = 0.f, a2 = 0.f, a3 = 0.f;
#pragma unroll 4
        for (int j = 0; j < 128; j++) {
            float xv = xr[j];                             // broadcast in wave
            float4v fv = *(const float4v*)(fc1_f + j * 128 + k0);  // coalesced
            a0 += xv * fv[0]; a1 += xv * fv[1];
            a2 += xv * fv[2]; a3 += xv * fv[3];
        }
        wefft[(k0 + 0) * 512 + n] = a0;       // one-time scattered stores
        wefft[(k0 + 1) * 512 + n] = a1;
        wefft[(k0 + 2) * 512 + n] = a2;
        wefft[(k0 + 3) * 512 + n] = a3;
        return;
    }
    int tg = (blockIdx.x - 64) * 256 + tid;   // 0..511
    float s = x2hb_f[tg] + h2hb_f[tg];
    const float4v* xr = (const float4v*)(x2h_f + tg * 128);
    const float4v* bb = (const float4v*)fc1b_f;
    for (int j = 0; j < 32; j++) {
        float4v a = xr[j], b = bb[j];
        s += a[0] * b[0] + a[1] * b[1] + a[2] * b[2] + a[3] * b[3];
    }
    beff[tg] = s;
}

// ---------------------------------------------------------------------------
// K2 (819 blocks x 256): table build + elementwise prep (r14-proven), with
// the CONV role vectorized (float4 -> us4 quads, one quad/thread, G13).
//  [0,256)   TABLE: bf16 tables, N-PERMUTED store (r13-verified bijection)
//  [256,512) XC:    x -> uchar2 t-major
//  [512,819) CONV:  Wh/fc2 f32->bf16 as quads; fc2b copy
// ---------------------------------------------------------------------------
__launch_bounds__(256)
__global__ void k2_kernel(const float* __restrict__ wefft, const float* __restrict__ beff,
                          const float* __restrict__ len_f, const float* __restrict__ ipd_f,
                          const int* __restrict__ xi, unsigned char* __restrict__ xc,
                          const float* __restrict__ h2h_f, const float* __restrict__ fc2_f,
                          const float* __restrict__ fc2b_f,
                          unsigned short* __restrict__ elen, unsigned short* __restrict__ eipd,
                          unsigned short* __restrict__ o_wh, unsigned short* __restrict__ o_fc2,
                          float* __restrict__ o_fc2b) {
    const int tid = threadIdx.x;
    if (blockIdx.x < 256) {
        int grp = blockIdx.x * 256 + tid;      // 0..65535
        int tab = grp >> 15;                   // 0: len, 1: ipd
        int g2  = grp & 32767;
        int v   = g2 >> 7;
        int nq  = (g2 & 127) * 4;              // logical n base (4 consecutive)
        const float* emb = (tab ? ipd_f : len_f) + v * 64;
        const float* wt  = wefft + tab * 64 * 512 + nq;
        float a0 = 0.f, a1 = 0.f, a2 = 0.f, a3 = 0.f;
#pragma unroll 8
        for (int k = 0; k < 64; k++) {
            float e = emb[k];
            float4v w = *(const float4v*)(wt + k * 512);
            a0 += e * w[0]; a1 += e * w[1]; a2 += e * w[2]; a3 += e * w[3];
        }
        if (tab) {
            float4v b4 = *(const float4v*)&beff[nq];
            a0 += b4[0]; a1 += b4[1]; a2 += b4[2]; a3 += b4[3];
        }
        // permuted store (r13/r14 HW-verified bijection)
        int nt = (nq >> 4) & 3, qq = (nq >> 2) & 3;
        int p0 = (nq & ~63) + ((nt >> 1) << 5) + qq * 8 + ((nt & 1) << 2);
        us4 o = { f2bf(a0), f2bf(a1), f2bf(a2), f2bf(a3) };
        unsigned short* dst = tab ? eipd : elen;
        *(us4*)&dst[v * 512 + p0] = o;
        return;
    }
    if (blockIdx.x < 512) {
        __shared__ int is64;
        if (tid == 0) {
            int nz = 0;
            for (int j = 1; j < 64; j += 2) nz |= xi[j];
            is64 = (nz == 0) ? 1 : 0;
        }
        __syncthreads();
        const int n = B_SZ * T_SZ * 2;
        const int i64 = is64;
        for (int i = (blockIdx.x - 256) * 256 + tid; i < n; i += 256 * 256) {
            int v = i64 ? xi[2 * i] : xi[i];
            v = v < 0 ? 0 : (v > 255 ? 255 : v);
            int b = i >> 8, r = i & 255, t = r >> 1, c = r & 1;
            xc[t * 2048 + b * 2 + c] = (unsigned char)v;
        }
        return;
    }
    // ---- CONV role, vectorized: 78336 quads + 100 scalars over 78592 thr ----
    const int NW4 = 65536;    // Wh quads (262144/4)
    const int NF4 = 12800;    // fc2 quads (51200/4)
    int gid = (blockIdx.x - 512) * 256 + tid;
    if (gid < NW4) {
        float4v a = *(const float4v*)(h2h_f + gid * 4);
        us4 o = { f2bf(a[0]), f2bf(a[1]), f2bf(a[2]), f2bf(a[3]) };
        *(us4*)&o_wh[gid * 4] = o;
    } else if (gid < NW4 + NF4) {
        int j = gid - NW4;
        float4v a = *(const float4v*)(fc2_f + j * 4);
        us4 o = { f2bf(a[0]), f2bf(a[1]), f2bf(a[2]), f2bf(a[3]) };
        *(us4*)&o_fc2[j * 4] = o;
    } else if (gid < NW4 + NF4 + 100) {
        int j = gid - NW4 - NF4;
        o_fc2b[j] = fc2b_f[j];
    }
}

// ---------------------------------------------------------------------------
// RNN v8 (BYTE-IDENTICAL to r14's proven 276 us kernel — compiled ALONE;
// r16 lesson: co-compiling any other role in this kernel degrades its
// codegen ~30% even with identical source).
// Structure: 64 blocks x 512 thr (8 waves, 2/SIMD — r3: 1/SIMD fails);
// Wh kt0..11 in 192 AGPRs (r1/r15: 224+ spills past the 320-reg/wave cliff,
// 640-reg/SIMD pool); kt12..15 in 128 KB swizzled LDS; h dbuf 32 KB;
// 1 barrier/step; fast tanh (rcp, no clamp); strength-reduced XOR addressing;
// bf16 N-permuted table gather as 4 x us8 (64 L1 lines/wave/step — r14: the
// gather cost is line-transactions, not bytes); uchar2 t-major idx;
// 2-deep software pipeline (idxP one step ahead, add at consume site).
// ---------------------------------------------------------------------------
__launch_bounds__(512, 2)
__global__ void rnn_kernel(const unsigned short* __restrict__ w_wh,
                           const unsigned char* __restrict__ w_xc,
                           const unsigned short* __restrict__ w_elen,
                           const unsigned short* __restrict__ w_eipd,
                           const unsigned short* __restrict__ w_fc2,
                           const float* __restrict__ w_fc2b,
                           float* __restrict__ out) {
    extern __shared__ unsigned short sm2[];
    unsigned short* sA = sm2;            // Wh k 384..511: 65536 ushorts (128 KB)
    unsigned short* sH = sm2 + 65536;    // h dbuf: 2 x 8192 ushorts (32 KB)

    const int tid  = threadIdx.x;
    const int wv   = tid >> 6;           // 0..7
    const int ln   = tid & 63;
    const int mcol = ln & 15;            // batch col within block
    const int q    = ln >> 4;
    const int g    = blockIdx.x;
    const int b0   = g * 16;
    const int n0   = wv * 64;            // wave owns hidden rows n0..n0+63

    // ---- stage Wh kt 12..15 into LDS (swizzled) ----
    for (int it = 0; it < 16; it++) {
        int chunk = it * 512 + tid;          // 0..8191
        int r = chunk >> 4, c = chunk & 15;
        uint4 v = *(const uint4*)(w_wh + r * 512 + 384 + c * 8);
        *(uint4*)&sA[r * 128 + ((c ^ (r & 15)) & 15) * 8] = v;
    }
    // ---- zero h buffer 0 ----
    {
        uint4 z = {0, 0, 0, 0};
        *(uint4*)&sH[tid * 8] = z;
        *(uint4*)&sH[(512 + tid) * 8] = z;
    }
    // ---- Wh kt 0..11 into registers: 48 frags = 192 regs (AGPR) ----
    short8 whr[4][12];
#pragma unroll
    for (int nt = 0; nt < 4; nt++)
#pragma unroll
        for (int kt = 0; kt < 12; kt++)
            whr[nt][kt] = *(const short8*)(w_wh + (n0 + nt * 16 + mcol) * 512 + kt * 32 + q * 8);

    // ---- strength-reduced swizzle offsets (ushort units) ----
    const int qlo = (q ^ (mcol & 3)) * 8;
    int ej[4];
#pragma unroll
    for (int j = 0; j < 4; j++)
        ej[j] = ((j * 4) ^ (mcol & 12)) * 8;
    const int base_b = mcol * 512 + qlo;          // h-read base
    const int fbase  = (n0 + mcol) * 128 + qlo;   // sA-read base
    int hw_off[4];
#pragma unroll
    for (int nt = 0; nt < 4; nt++) {
        int n = n0 + nt * 16 + q * 4;
        hw_off[nt] = mcol * 512 + (((n >> 3) ^ mcol) & 63) * 8 + (n & 7);
    }

    // ---- gather pipeline prologue (permuted bf16 tables, uchar2 idx) ----
    const int xb2  = (b0 + mcol) * 2;     // byte offset within a t-slice
    const int ecol = n0 + q * 8;          // permuted window offset
    us8 tL0, tL1, tI0, tI1;
    {
        unsigned int i0 = *(const unsigned short*)&w_xc[xb2];          // x[t=0]
        const unsigned short* eL = w_elen + (i0 & 255u) * 512 + ecol;
        const unsigned short* eI = w_eipd + (i0 >> 8) * 512 + ecol;
        tL0 = *(const us8*)eL;  tL1 = *(const us8*)(eL + 32);
        tI0 = *(const us8*)eI;  tI1 = *(const us8*)(eI + 32);
    }
    unsigned int idxP = *(const unsigned short*)&w_xc[2048 + xb2];     // x[t=1]

    __syncthreads();

    for (int t = 0; t < T_SZ; t++) {
        const unsigned short* hRd = sH + ((t & 1) << 13);
        unsigned short* hWr = sH + (((t + 1) & 1) << 13);

        // ---- acc init: unpack permuted us8 pairs (loads from t-1, landed) --
        float4v acc[4];
#pragma unroll
        for (int r = 0; r < 4; r++) {
            acc[0][r] = bf2f(tL0[r])     + bf2f(tI0[r]);
            acc[1][r] = bf2f(tL0[4 + r]) + bf2f(tI0[4 + r]);
            acc[2][r] = bf2f(tL1[r])     + bf2f(tI1[r]);
            acc[3][r] = bf2f(tL1[4 + r]) + bf2f(tI1[4 + r]);
        }
        // ---- issue next-step table loads (idxP resident -> no chain) ----
        if (t + 1 < T_SZ) {
            const unsigned short* eL = w_elen + (idxP & 255u) * 512 + ecol;
            const unsigned short* eI = w_eipd + (idxP >> 8) * 512 + ecol;
            tL0 = *(const us8*)eL;  tL1 = *(const us8*)(eL + 32);
            tI0 = *(const us8*)eI;  tI1 = *(const us8*)(eI + 32);
            if (t + 2 < T_SZ)
                idxP = *(const unsigned short*)&w_xc[(t + 2) * 2048 + xb2];
        }

        // ---- Wh MFMAs: kt 0..11 from regs ----
#pragma unroll
        for (int kt = 0; kt < 12; kt++) {
            short8 bh = *(const short8*)&hRd[base_b + ej[kt & 3] + (kt >> 2) * 128];
#pragma unroll
            for (int nt = 0; nt < 4; nt++)
                acc[nt] = mfma16(whr[nt][kt], bh, acc[nt]);
        }
        // ---- kt 12..15 from LDS ----
#pragma unroll
        for (int j = 0; j < 4; j++) {
            short8 bh = *(const short8*)&hRd[base_b + ej[j] + 384];
#pragma unroll
            for (int nt = 0; nt < 4; nt++) {
                short8 fa = *(const short8*)&sA[fbase + nt * 2048 + ej[j]];
                acc[nt] = mfma16(fa, bh, acc[nt]);
            }
        }

        // ---- fast tanh -> bf16, write h(t+1) into other buffer ----
#pragma unroll
        for (int nt = 0; nt < 4; nt++) {
            unsigned short o[4];
#pragma unroll
            for (int r = 0; r < 4; r++) {
                float e  = __expf(2.0f * acc[nt][r]);
                float th = 1.0f - 2.0f * __builtin_amdgcn_rcpf(e + 1.0f);
                o[r] = f2bf(th);
            }
            us4 v4 = { o[0], o[1], o[2], o[3] };
            *(us4*)&hWr[hw_off[nt]] = v4;
        }
        __syncthreads();   // h(t+1) visible to all waves before next step
    }

    // final h is in buffer 0 (T_SZ even)
    unsigned short* hF = sH;

    // ---- fc2 epilogue: waves 0..6 cover 112 >= 100 labels ----
    if (wv < 7) {
        int lA = wv * 16 + mcol; if (lA > 99) lA = 99;
        float4v a2 = {0.f, 0.f, 0.f, 0.f};
#pragma unroll
        for (int kt = 0; kt < 16; kt++) {
            short8 fa = *(const short8*)(w_fc2 + lA * 512 + kt * 32 + q * 8);
            short8 bh = *(const short8*)&hF[base_b + ej[kt & 3] + (kt >> 2) * 128];
            a2 = mfma16(fa, bh, a2);
        }
#pragma unroll
        for (int r = 0; r < 4; r++) {
            int l = wv * 16 + q * 4 + r;
            if (l < 100) out[(b0 + mcol) * 100 + l] = a2[r] + w_fc2b[l];
        }
    }
}

extern "C" void kernel_launch(void* const* d_in, const int* in_sizes, int n_in,
                              void* d_out, int out_size, void* d_ws, size_t ws_size,
                              hipStream_t stream) {
    unsigned char* base = (unsigned char*)d_ws;
    if (ws_size < (size_t)WS_NEED) {
        void* p = nullptr;
        hipGetSymbolAddress(&p, HIP_SYMBOL(g_blob));
        base = (unsigned char*)p;
    }
    unsigned char*  w_xc    = base + OFF_XC;
    unsigned short* w_wh    = (unsigned short*)(base + OFF_WH);
    unsigned short* w_fc2   = (unsigned short*)(base + OFF_FC2);
    float*          w_fc2b  = (float*)(base + OFF_FC2B);
    float*          w_wefft = (float*)(base + OFF_WEFFT);
    float*          w_beff  = (float*)(base + OFF_BEFF);
    unsigned short* w_elen  = (unsigned short*)(base + OFF_ELEN);
    unsigned short* w_eipd  = (unsigned short*)(base + OFF_EIPD);

    static bool attr_set = false;
    if (!attr_set) {
        hipFuncSetAttribute((const void*)rnn_kernel,
                            hipFuncAttributeMaxDynamicSharedMemorySize, 163840);
        attr_set = true;
    }

    k1_kernel<<<66, 256, 0, stream>>>(
        (const float*)d_in[3], (const float*)d_in[4],
        (const float*)d_in[5], (const float*)d_in[6], (const float*)d_in[8],
        w_wefft, w_beff);
    k2_kernel<<<819, 256, 0, stream>>>(
        w_wefft, w_beff,
        (const float*)d_in[1], (const float*)d_in[2],
        (const int*)d_in[0], w_xc,
        (const float*)d_in[7], (const float*)d_in[9], (const float*)d_in[10],
        w_elen, w_eipd, w_wh, w_fc2, w_fc2b);
    rnn_kernel<<<64, 512, 163840, stream>>>(
        w_wh, w_xc, w_elen, w_eipd, w_fc2, w_fc2b, (float*)d_out);
}